// Round 1
// 410.421 us; speedup vs baseline: 1.0856x; 1.0856x over previous
//
#include <hip/hip_runtime.h>

#define BATCH 4096
#define NGC   8192
#define NPC   2048

typedef _Float16 f16;
typedef __attribute__((ext_vector_type(8))) _Float16 f16x8;
typedef __attribute__((ext_vector_type(4))) _Float16 f16x4;
typedef __attribute__((ext_vector_type(4))) float   floatx4;

__device__ __forceinline__ float softplus_f(float x) {
    // jax.nn.softplus = log1p(exp(-|x|)) + max(x, 0)
    return fmaxf(x, 0.0f) + log1pf(expf(-fabsf(x)));
}

// ---- prep: g_in f32 -> f16 -------------------------------------------------
__global__ void cvt_g(const float* __restrict__ g, f16* __restrict__ gh) {
    int i = (blockIdx.x * blockDim.x + threadIdx.x) * 4;
    float4 v = *(const float4*)(g + i);
    f16x4 h;
    h[0] = (f16)v.x; h[1] = (f16)v.y; h[2] = (f16)v.z; h[3] = (f16)v.w;
    *(f16x4*)(gh + i) = h;
}

// ---- prep: W = softplus(W_raw) * mask -> f16 -------------------------------
__global__ void cvt_w(const float* __restrict__ W, const float* __restrict__ mask,
                      f16* __restrict__ wh) {
    int i = (blockIdx.x * blockDim.x + threadIdx.x) * 4;
    float4 w = *(const float4*)(W + i);
    float4 m = *(const float4*)(mask + i);
    f16x4 h;
    h[0] = (f16)(softplus_f(w.x) * m.x);
    h[1] = (f16)(softplus_f(w.y) * m.y);
    h[2] = (f16)(softplus_f(w.z) * m.z);
    h[3] = (f16)(softplus_f(w.w) * m.w);
    *(f16x4*)(wh + i) = h;
}

// ---- main GEMM -------------------------------------------------------------
// out[b][p] = relu(sum_k A[b][k]*B[p][k] + bias[p])
//
// v2: counted-vmcnt pipelined schedule (T3+T4) on a 256x128 tile.
//   BM=256 (batch), BN=128 (pc), BK=64. 512 thr = 8 waves (4M x 2N),
//   wave tile 64x64 = 4x4 frags of 16x16x32 f16 MFMA.
//   Grid (16,16) = 256 blocks = exactly 1 block/CU (LDS 144KB -> 1 block/CU).
//
//   THREE rotating K-tile LDS buffers (48KB each) make the counted wait exact
//   and race-free with ONE barrier per K-tile and NO vmcnt(0) drain in the loop:
//     - computing tile t (buf t%3), tile t+1 fully in flight (buf (t+1)%3),
//       tile t+2's loads issued into buf (t+2)%3 (its last reader was tile t-1,
//       whose reads all completed before the top-of-t barrier -> no race).
//     - top of tile t: s_waitcnt vmcnt(6) (6 = t+1's loads still flying)
//       guarantees t's loads retired (vmcnt retires in issue order), then one
//       raw s_barrier. Each wave passes its own vmcnt before the barrier, so
//       after the barrier ALL slices of buf t%3 are visible. Last tile: vmcnt(0).
//
// XOR-swizzled staging kept from v1 (measured SQ_LDS_BANK_CONFLICT = 0):
// LDS chunk d (16B) holds global k-group g = (d&7)^(r&7), r = d>>3.
__device__ __forceinline__ void gload_lds16(const f16* g, f16* l) {
    __builtin_amdgcn_global_load_lds((const __attribute__((address_space(1))) void*)g,
                                     (__attribute__((address_space(3))) void*)l,
                                     16, 0, 0);
}

#define ABUF  (256 * 64)          // f16 elems per A tile (32 KB)
#define BBUF  (128 * 64)          // f16 elems per B tile (16 KB)
#define BUFSZ (ABUF + BBUF)       // 24576 f16 = 48 KB
#define NT    (NGC / 64)          // 128 K-tiles

// A tile: 2048 chunks of 16B -> 4 loads/thread; B tile: 1024 -> 2 loads/thread.
#define STAGE_A(kt, sbuf, i) do {                                              \
    int d_ = tid + 512 * (i);                                                  \
    int r_ = d_ >> 3;                                                          \
    int g_ = (d_ & 7) ^ (r_ & 7);                                              \
    gload_lds16(A + (size_t)(bm0 + r_) * NGC + (kt) * 64 + g_ * 8,             \
                (sbuf) + d_ * 8);                                              \
} while (0)

#define STAGE_B(kt, sbuf, i) do {                                              \
    int d_ = tid + 512 * (i);                                                  \
    int r_ = d_ >> 3;                                                          \
    int g_ = (d_ & 7) ^ (r_ & 7);                                              \
    gload_lds16(B + (size_t)(bn0 + r_) * NGC + (kt) * 64 + g_ * 8,             \
                (sbuf) + ABUF + d_ * 8);                                       \
} while (0)

__global__ __launch_bounds__(512, 2)
void gemm_f16(const f16* __restrict__ A, const f16* __restrict__ B,
              const float* __restrict__ bias, float* __restrict__ out) {
    __shared__ __align__(16) f16 lds[3 * BUFSZ];   // 144 KB

    const int tid  = threadIdx.x;
    const int lane = tid & 63;
    const int wid  = tid >> 6;
    const int bm0  = blockIdx.y * 256;   // batch
    const int bn0  = blockIdx.x * 128;   // pc
    const int wm   = (wid >> 1) * 64;    // 4 M-wave groups
    const int wn   = (wid & 1) * 64;     // 2 N-wave groups
    const int l15  = lane & 15;
    const int lq   = lane >> 4;

    floatx4 acc[4][4] = {};

    // prologue: tiles 0 and 1 fully issued (12 loads/thread in flight)
#pragma unroll
    for (int i = 0; i < 4; ++i) STAGE_A(0, lds, i);
#pragma unroll
    for (int i = 0; i < 2; ++i) STAGE_B(0, lds, i);
#pragma unroll
    for (int i = 0; i < 4; ++i) STAGE_A(1, lds + BUFSZ, i);
#pragma unroll
    for (int i = 0; i < 2; ++i) STAGE_B(1, lds + BUFSZ, i);

    int cur = 0;
    for (int t = 0; t < NT; ++t) {
        // counted wait: tile t retired, tile t+1's 6 loads stay in flight.
        if (t + 1 < NT) asm volatile("s_waitcnt vmcnt(6)" ::: "memory");
        else            asm volatile("s_waitcnt vmcnt(0)" ::: "memory");
        __builtin_amdgcn_s_barrier();

        f16* sA = lds + cur * BUFSZ;
        f16* sB = sA + ABUF;
        int st = cur + 2; if (st >= 3) st -= 3;
        f16* stbuf = lds + st * BUFSZ;
        const bool do_stage = (t < NT - 2);

#pragma unroll
        for (int ks = 0; ks < 2; ++ks) {
            const int g = ks * 4 + lq;   // k-group for this lane's fragment
            f16x8 a[4], b[4];
#pragma unroll
            for (int mt = 0; mt < 4; ++mt) {
                int ra = wm + mt * 16 + l15;
                int ca = (ra << 3) | (g ^ (ra & 7));
                a[mt] = *(const f16x8*)(sA + ca * 8);
            }
#pragma unroll
            for (int nt = 0; nt < 4; ++nt) {
                int rb = wn + nt * 16 + l15;
                int cb = (rb << 3) | (g ^ (rb & 7));
                b[nt] = *(const f16x8*)(sB + cb * 8);
            }
            // issue half of tile t+2's staging (3 loads) under this phase's MFMAs
            if (do_stage) {
                STAGE_A(t + 2, stbuf, ks * 2 + 0);
                STAGE_A(t + 2, stbuf, ks * 2 + 1);
                STAGE_B(t + 2, stbuf, ks);
            }
            __builtin_amdgcn_s_setprio(1);
#pragma unroll
            for (int mt = 0; mt < 4; ++mt)
#pragma unroll
                for (int nt = 0; nt < 4; ++nt)
                    acc[mt][nt] = __builtin_amdgcn_mfma_f32_16x16x32_f16(
                        a[mt], b[nt], acc[mt][nt], 0, 0, 0);
            __builtin_amdgcn_s_setprio(0);
        }
        cur += 1; if (cur == 3) cur = 0;
    }

    // epilogue: D layout col=lane&15 (pc), row=(lane>>4)*4+reg (batch)
#pragma unroll
    for (int nt = 0; nt < 4; ++nt) {
        int col  = bn0 + wn + nt * 16 + l15;
        float bv = bias[col];
#pragma unroll
        for (int mt = 0; mt < 4; ++mt) {
#pragma unroll
            for (int r = 0; r < 4; ++r) {
                int row = bm0 + wm + mt * 16 + lq * 4 + r;
                float x = acc[mt][nt][r] + bv;
                out[(size_t)row * NPC + col] = fmaxf(x, 0.0f);
            }
        }
    }
}

// ---- exact fp32 fallback (only if ws too small) ----------------------------
__global__ void naive_kernel(const float* __restrict__ g, const float* __restrict__ W,
                             const float* __restrict__ bias, const float* __restrict__ mask,
                             float* __restrict__ out) {
    int idx = blockIdx.x * 256 + threadIdx.x;   // over BATCH*NPC
    int b = idx / NPC, p = idx % NPC;
    const float* gr = g + (size_t)b * NGC;
    const float* wr = W + (size_t)p * NGC;
    const float* mr = mask + (size_t)p * NGC;
    float acc = bias[p];
    for (int k = 0; k < NGC; ++k) {
        float m = mr[k];
        if (m != 0.0f) acc += gr[k] * softplus_f(wr[k]);
    }
    out[idx] = fmaxf(acc, 0.0f);
}

extern "C" void kernel_launch(void* const* d_in, const int* in_sizes, int n_in,
                              void* d_out, int out_size, void* d_ws, size_t ws_size,
                              hipStream_t stream) {
    const float* g_in  = (const float*)d_in[0];
    const float* W_raw = (const float*)d_in[1];
    const float* b_pc  = (const float*)d_in[2];
    const float* mask  = (const float*)d_in[3];
    float* out = (float*)d_out;

    const size_t gh_elems = (size_t)BATCH * NGC;
    const size_t wh_elems = (size_t)NPC * NGC;
    const size_t need = (gh_elems + wh_elems) * sizeof(f16);   // 96 MB

    if (ws_size >= need) {
        f16* gh = (f16*)d_ws;
        f16* wh = gh + gh_elems;
        cvt_g<<<(int)(gh_elems / 1024), 256, 0, stream>>>(g_in, gh);
        cvt_w<<<(int)(wh_elems / 1024), 256, 0, stream>>>(W_raw, mask, wh);
        dim3 grid(NPC / 128, BATCH / 256);
        gemm_f16<<<grid, 512, 0, stream>>>(gh, wh, b_pc, out);
    } else {
        naive_kernel<<<BATCH * NPC / 256, 256, 0, stream>>>(g_in, W_raw, b_pc, mask, out);
    }
}